// Round 1
// baseline (358.888 us; speedup 1.0000x reference)
//
#include <hip/hip_runtime.h>

typedef __attribute__((ext_vector_type(8))) short short8;
typedef __attribute__((ext_vector_type(4))) float f32x4;

#define S_LEN 2048
#define DH 64

__device__ __forceinline__ unsigned short f2bf(float x) {
  unsigned u = __builtin_bit_cast(unsigned, x);
  u += 0x7fffu + ((u >> 16) & 1u);
  return (unsigned short)(u >> 16);
}

// ---- detect whether mask was passed as uint8 (stride 1) or int32 (stride 4)
__global__ void detect_stride_k(const unsigned char* __restrict__ m, int* flag) {
  __shared__ int any;
  if (threadIdx.x == 0) any = 0;
  __syncthreads();
  int acc = 0;
  for (int i = threadIdx.x; i < 4096; i += 256)
    if (i & 3) acc |= m[i];
  if (acc) atomicOr(&any, 1);
  __syncthreads();
  if (threadIdx.x == 0) *flag = any ? 1 : 4;
}

// ---- K: f32 -> bf16, row-major [bh][t][d]
__global__ void conv_k_kernel(const float* __restrict__ k, char* __restrict__ kbf) {
  int idx = blockIdx.x * 256 + threadIdx.x;  // 524288 threads, 8 elems each
  const float4* s = (const float4*)k + (size_t)idx * 2;
  float4 a = s[0], b = s[1];
  int4 o;
  o.x = (int)f2bf(a.x) | ((int)f2bf(a.y) << 16);
  o.y = (int)f2bf(a.z) | ((int)f2bf(a.w) << 16);
  o.z = (int)f2bf(b.x) | ((int)f2bf(b.y) << 16);
  o.w = (int)f2bf(b.z) | ((int)f2bf(b.w) << 16);
  ((int4*)kbf)[idx] = o;
}

// ---- V: f32 [bh][t][d] -> bf16 transposed [bh][d][t]
__global__ void trans_v_kernel(const float* __restrict__ v, char* __restrict__ vtbf) {
  int gt = blockIdx.x * 256 + threadIdx.x;
  int wid = gt >> 6;            // 16384 wave-jobs
  int lane = gt & 63;
  int bh = wid >> 9;
  int rem = wid & 511;
  int d0 = (rem >> 5) * 4;      // 0,4,...,60
  int t = (rem & 31) * 64 + lane;
  float4 val = *(const float4*)(v + ((size_t)bh * S_LEN + t) * DH + d0);
  unsigned short* o = (unsigned short*)vtbf;
  size_t base = ((size_t)bh * DH + d0) * S_LEN + t;
  o[base]             = f2bf(val.x);
  o[base + S_LEN]     = f2bf(val.y);
  o[base + 2 * S_LEN] = f2bf(val.z);
  o[base + 3 * S_LEN] = f2bf(val.w);
}

__global__ __launch_bounds__(256, 2)
void attn_main(const float* __restrict__ qsrc,
               const unsigned char* __restrict__ maskb,
               const char* __restrict__ kbf,
               const char* __restrict__ vtbf,
               const int* __restrict__ flagp,
               float* __restrict__ out) {
  __shared__ __align__(16) char kbuf[16384];   // K tile [128 t][64 d] bf16, XOR-swizzled
  __shared__ __align__(16) char vbuf[16384];   // V^T tile [64 d][128 t] bf16, XOR-swizzled
  __shared__ __align__(16) char pbuf[32768];   // per-wave P [32 q][128 t] bf16, XOR-swizzled

  const int tid = threadIdx.x;
  const int lane = tid & 63;
  const int w = tid >> 6;
  const int l15 = lane & 15;
  const int g = lane >> 4;
  const int sw = (l15 & 7) << 4;

  // XCD-aware bijective swizzle: 512 blocks, 8 XCDs -> 4 consecutive bh per XCD
  int raw = blockIdx.x;
  int swz = (raw & 7) * 64 + (raw >> 3);
  const int bh = swz >> 4;
  const int rowblk = swz & 15;
  const int b = bh >> 4;
  const int q0 = rowblk * 128 + w * 32;

  const int stride = *flagp;
  const unsigned char* mb = maskb + (size_t)b * S_LEN * S_LEN * (size_t)stride;

  // Q fragments (B operand of swapped QK^T): lane holds Q[q0+16qs+l15][32kc+8g+j]
  short8 qf[2][2];
#pragma unroll
  for (int qs = 0; qs < 2; ++qs)
#pragma unroll
    for (int kc = 0; kc < 2; ++kc) {
      const float* qp = qsrc + ((size_t)bh * S_LEN + q0 + 16 * qs + l15) * DH + 32 * kc + 8 * g;
      float4 x = *(const float4*)qp;
      float4 y = *(const float4*)(qp + 4);
      short8 f;
      f[0] = (short)f2bf(x.x); f[1] = (short)f2bf(x.y);
      f[2] = (short)f2bf(x.z); f[3] = (short)f2bf(x.w);
      f[4] = (short)f2bf(y.x); f[5] = (short)f2bf(y.y);
      f[6] = (short)f2bf(y.z); f[7] = (short)f2bf(y.w);
      qf[qs][kc] = f;
    }

  f32x4 acc[4][2];
#pragma unroll
  for (int i = 0; i < 4; ++i)
#pragma unroll
    for (int j = 0; j < 2; ++j)
      acc[i][j] = (f32x4){0.f, 0.f, 0.f, 0.f};
  float lpart[2] = {0.f, 0.f};

  const char* ksrc_bh = kbf + (size_t)bh * (S_LEN * DH * 2);
  const char* vsrc_bh = vtbf + (size_t)bh * (DH * S_LEN * 2);

  // ---------------- PASS A: l-sum + results = score @ V ----------------
  for (int t0 = 0; t0 < S_LEN; t0 += 128) {
    __syncthreads();
    {  // stage K tile
      int rr = tid >> 3, cc = tid & 7;
      const char* src = ksrc_bh + (size_t)t0 * 128;
#pragma unroll
      for (int it = 0; it < 4; ++it) {
        int r = it * 32 + rr;
        int4 val = *(const int4*)(src + r * 128 + cc * 16);
        *(int4*)(kbuf + r * 128 + ((cc * 16) ^ ((r & 7) << 4))) = val;
      }
    }
    {  // stage V^T tile
      int rr = tid >> 4, cc = tid & 15;
      const char* src = vsrc_bh + (size_t)t0 * 2;
#pragma unroll
      for (int it = 0; it < 4; ++it) {
        int r = it * 16 + rr;
        int4 val = *(const int4*)(src + (size_t)r * (S_LEN * 2) + cc * 16);
        *(int4*)(vbuf + r * 256 + ((cc * 16) ^ ((r & 7) << 4))) = val;
      }
    }
    __syncthreads();

    // GEMM1 (swapped): S^T frag, lane holds S[q=l15+16qs][t=t0+16tc+4g+r]
    f32x4 sf[2][8];
#pragma unroll
    for (int tc = 0; tc < 8; ++tc) {
      const char* rowp = kbuf + (16 * tc + l15) * 128;
      short8 a0 = *(const short8*)(rowp + ((16 * g) ^ sw));
      short8 a1 = *(const short8*)(rowp + ((64 + 16 * g) ^ sw));
      f32x4 z = (f32x4){0.f, 0.f, 0.f, 0.f};
      f32x4 t00 = __builtin_amdgcn_mfma_f32_16x16x32_bf16(a0, qf[0][0], z, 0, 0, 0);
      sf[0][tc]  = __builtin_amdgcn_mfma_f32_16x16x32_bf16(a1, qf[0][1], t00, 0, 0, 0);
      f32x4 t10 = __builtin_amdgcn_mfma_f32_16x16x32_bf16(a0, qf[1][0], z, 0, 0, 0);
      sf[1][tc]  = __builtin_amdgcn_mfma_f32_16x16x32_bf16(a1, qf[1][1], t10, 0, 0, 0);
    }

    // mask + scale + exp-sum + pack P to LDS
    char* pb_w = pbuf + w * 8192;
#pragma unroll
    for (int qs = 0; qs < 2; ++qs) {
      const int q = q0 + 16 * qs + l15;
      char* pb = pb_w + (16 * qs + l15) * 256;
#pragma unroll
      for (int tc = 0; tc < 8; ++tc) {
        const int t = t0 + 16 * tc + 4 * g;
        size_t eidx = (size_t)q * S_LEN + t;
        int m0, m1, m2, m3;
        if (stride == 1) {
          unsigned mv = *(const unsigned*)(mb + eidx);
          m0 = mv & 0xff; m1 = (mv >> 8) & 0xff; m2 = (mv >> 16) & 0xff; m3 = (mv >> 24) & 0xff;
        } else {
          uint4 mv = *(const uint4*)(mb + eidx * 4);
          m0 = mv.x; m1 = mv.y; m2 = mv.z; m3 = mv.w;
        }
        float s0 = m0 ? -1e9f : sf[qs][tc][0] * 0.125f;
        float s1 = m1 ? -1e9f : sf[qs][tc][1] * 0.125f;
        float s2 = m2 ? -1e9f : sf[qs][tc][2] * 0.125f;
        float s3 = m3 ? -1e9f : sf[qs][tc][3] * 0.125f;
        lpart[qs] += __expf(s0) + __expf(s1) + __expf(s2) + __expf(s3);
        int2 pk;
        pk.x = (int)f2bf(s0) | ((int)f2bf(s1) << 16);
        pk.y = (int)f2bf(s2) | ((int)f2bf(s3) << 16);
        *(int2*)(pb + ((32 * tc + 8 * g) ^ sw)) = pk;
      }
    }

    // GEMM2: acc^T[d][q] += V^T · P^T (same lane->k fill convention on A and B)
#pragma unroll
    for (int kc2 = 0; kc2 < 4; ++kc2) {
      const int rc = (64 * kc2 + 16 * g) ^ sw;
      short8 p0 = *(const short8*)(pb_w + l15 * 256 + rc);
      short8 p1 = *(const short8*)(pb_w + (16 + l15) * 256 + rc);
#pragma unroll
      for (int dr = 0; dr < 4; ++dr) {
        short8 aV = *(const short8*)(vbuf + (16 * dr + l15) * 256 + rc);
        acc[dr][0] = __builtin_amdgcn_mfma_f32_16x16x32_bf16(aV, p0, acc[dr][0], 0, 0, 0);
        acc[dr][1] = __builtin_amdgcn_mfma_f32_16x16x32_bf16(aV, p1, acc[dr][1], 0, 0, 0);
      }
    }
  }

  // softmax denominators (rows live on lanes {l, l+16, l+32, l+48})
  float inv[2];
#pragma unroll
  for (int qs = 0; qs < 2; ++qs) {
    float l = lpart[qs];
    l += __shfl_xor(l, 16);
    l += __shfl_xor(l, 32);
    inv[qs] = 1.0f / l;
  }

  // write results: acc^T C-layout -> out[bh][q][d], float4 along d
#pragma unroll
  for (int dr = 0; dr < 4; ++dr)
#pragma unroll
    for (int qs = 0; qs < 2; ++qs) {
      const int q = q0 + 16 * qs + l15;
      float4 o;
      o.x = acc[dr][qs][0]; o.y = acc[dr][qs][1];
      o.z = acc[dr][qs][2]; o.w = acc[dr][qs][3];
      *(float4*)(out + ((size_t)bh * S_LEN + q) * DH + 16 * dr + 4 * g) = o;
    }

  // ---------------- PASS B: recompute scores, write attention ----------------
  float* att = out + (size_t)4194304 + (size_t)bh * S_LEN * S_LEN;
  for (int t0 = 0; t0 < S_LEN; t0 += 128) {
    __syncthreads();
    {  // stage K tile
      int rr = tid >> 3, cc = tid & 7;
      const char* src = ksrc_bh + (size_t)t0 * 128;
#pragma unroll
      for (int it = 0; it < 4; ++it) {
        int r = it * 32 + rr;
        int4 val = *(const int4*)(src + r * 128 + cc * 16);
        *(int4*)(kbuf + r * 128 + ((cc * 16) ^ ((r & 7) << 4))) = val;
      }
    }
    __syncthreads();

    f32x4 sf[2][8];
#pragma unroll
    for (int tc = 0; tc < 8; ++tc) {
      const char* rowp = kbuf + (16 * tc + l15) * 128;
      short8 a0 = *(const short8*)(rowp + ((16 * g) ^ sw));
      short8 a1 = *(const short8*)(rowp + ((64 + 16 * g) ^ sw));
      f32x4 z = (f32x4){0.f, 0.f, 0.f, 0.f};
      f32x4 t00 = __builtin_amdgcn_mfma_f32_16x16x32_bf16(a0, qf[0][0], z, 0, 0, 0);
      sf[0][tc]  = __builtin_amdgcn_mfma_f32_16x16x32_bf16(a1, qf[0][1], t00, 0, 0, 0);
      f32x4 t10 = __builtin_amdgcn_mfma_f32_16x16x32_bf16(a0, qf[1][0], z, 0, 0, 0);
      sf[1][tc]  = __builtin_amdgcn_mfma_f32_16x16x32_bf16(a1, qf[1][1], t10, 0, 0, 0);
    }

#pragma unroll
    for (int qs = 0; qs < 2; ++qs) {
      const int q = q0 + 16 * qs + l15;
#pragma unroll
      for (int tc = 0; tc < 8; ++tc) {
        const int t = t0 + 16 * tc + 4 * g;
        size_t eidx = (size_t)q * S_LEN + t;
        int m0, m1, m2, m3;
        if (stride == 1) {
          unsigned mv = *(const unsigned*)(mb + eidx);
          m0 = mv & 0xff; m1 = (mv >> 8) & 0xff; m2 = (mv >> 16) & 0xff; m3 = (mv >> 24) & 0xff;
        } else {
          uint4 mv = *(const uint4*)(mb + eidx * 4);
          m0 = mv.x; m1 = mv.y; m2 = mv.z; m3 = mv.w;
        }
        float s0 = m0 ? -1e9f : sf[qs][tc][0] * 0.125f;
        float s1 = m1 ? -1e9f : sf[qs][tc][1] * 0.125f;
        float s2 = m2 ? -1e9f : sf[qs][tc][2] * 0.125f;
        float s3 = m3 ? -1e9f : sf[qs][tc][3] * 0.125f;
        float4 e;
        e.x = __expf(s0) * inv[qs];
        e.y = __expf(s1) * inv[qs];
        e.z = __expf(s2) * inv[qs];
        e.w = __expf(s3) * inv[qs];
        *(float4*)(att + (size_t)q * S_LEN + t) = e;
      }
    }
  }
}

extern "C" void kernel_launch(void* const* d_in, const int* in_sizes, int n_in,
                              void* d_out, int out_size, void* d_ws, size_t ws_size,
                              hipStream_t stream) {
  (void)in_sizes; (void)n_in; (void)out_size; (void)ws_size;
  const float* q = (const float*)d_in[0];
  const float* k = (const float*)d_in[1];
  const float* v = (const float*)d_in[2];
  const unsigned char* mask = (const unsigned char*)d_in[3];
  float* out = (float*)d_out;

  char* ws = (char*)d_ws;
  int* flag = (int*)ws;
  char* kbf = ws + 256;                       // 8 MiB bf16 K
  char* vtbf = ws + 256 + 8 * 1024 * 1024;    // 8 MiB bf16 V^T

  detect_stride_k<<<1, 256, 0, stream>>>(mask, flag);
  conv_k_kernel<<<2048, 256, 0, stream>>>(k, kbf);
  trans_v_kernel<<<4096, 256, 0, stream>>>(v, vtbf);
  attn_main<<<512, 256, 0, stream>>>(q, mask, kbf, vtbf, flag, out);
}